// Round 9
// baseline (955.182 us; speedup 1.0000x reference)
//
#include <hip/hip_runtime.h>

// R9 = R7/R8 inner layouts, re-decomposed for 2x occupancy:
//   block = 256 thr = 4 waves = 2 SAMPLES (was 4), grid = 1024 (was 512)
//   -> 4096 waves = 4 waves/SIMD (was 2), 4 blocks/CU, LDS ~25 KB.
// Rationale: R8 counters show no pipe >65% busy (LDS ~64%, VALU 42%,
// MFMA 22%) -> TLP-starved serial chains, not pipe-bound. Work per CU is
// conserved; doubled TLP fills the overlap deficit.
// Wave w: oc-tile [16w,16w+16), N = 32 padded cols (18 valid = 2 samples
// x 9 pos): 2 nt-tiles, 8 b128 B-loads, 24 MFMA, 6 acc chains.
// fc/LIF3: wave 0 -> sample 0, wave 1 -> sample 1; waves 2,3 skip fc and
// start GEMM loads early (intra-block desync).
// Numerics: 3-level nested i8 (~fp32-grade), exact i32 accumulation,
// sigma-permuted scatter layout word(ic,ky) = 4ic + ((ky+ic)&3).

#define NSTEPS 100
#define IMSTRIDE 272
#define NCOLS 32
#define ZIMG (NCOLS * IMSTRIDE)   // 8704 B per parity buffer
#define Z2S 612                   // shorts per (sample, step)
#define Z2PAR (2 * Z2S)           // shorts per parity (2 samples)

typedef __attribute__((ext_vector_type(4))) int i32x4;

// conv1 + 2x2 maxpool for one spike-row (sample, ic, y): 6 outputs
__device__ __forceinline__ void conv1_row(const float* __restrict__ xs,
                                          const float* __restrict__ w1s,
                                          float b1v, int y, float* cur) {
    float cr[2][12];
    #pragma unroll
    for (int rr = 0; rr < 2; ++rr) {
        const int cy = 2 * y + rr;
        #pragma unroll
        for (int cx = 0; cx < 12; ++cx) {
            float a = 0.f;
            #pragma unroll
            for (int ky = 0; ky < 4; ++ky)
            #pragma unroll
            for (int kx = 0; kx < 4; ++kx)
                a = fmaf(xs[(cy + ky) * 16 + cx + kx], w1s[ky * 4 + kx], a);
            cr[rr][cx] = a + b1v;
        }
    }
    #pragma unroll
    for (int px = 0; px < 6; ++px)
        cur[px] = fmaxf(fmaxf(cr[0][2 * px], cr[0][2 * px + 1]),
                        fmaxf(cr[1][2 * px], cr[1][2 * px + 1]));
}

// LIF1 step for one spike-row + sigma-permuted i8 scatter.
// pb = zimg_parity_base + (9*sl + 3*y)*IMSTRIDE + 16*ic
__device__ __forceinline__ void lif1_row(float* v1, float* i1, const float* cur,
                                         unsigned char* pb, int ic, int y) {
    unsigned zb[6];
    #pragma unroll
    for (int xx = 0; xx < 6; ++xx) {
        const float vd = v1[xx] + 0.1f * (i1[xx] - v1[xx]);
        i1[xx] = i1[xx] * 0.8f + cur[xx];
        const bool sp = vd > 1.0f;
        v1[xx] = sp ? 0.0f : vd;
        zb[xx] = sp ? 1u : 0u;
    }
    const unsigned q0 = zb[0] | (zb[1] << 8) | (zb[2] << 16) | (zb[3] << 24);
    const unsigned q1 = zb[1] | (zb[2] << 8) | (zb[3] << 16) | (zb[4] << 24);
    const unsigned q2 = zb[2] | (zb[3] << 8) | (zb[4] << 16) | (zb[5] << 24);
    #pragma unroll
    for (int ky = 0; ky < 4; ++ky) {
        const int py = y - ky;
        if (0 <= py && py <= 2) {
            unsigned char* b = pb - ky * (3 * IMSTRIDE) + 4 * ((ky + ic) & 3);
            *(unsigned*)(b)                = q0;   // px = 0
            *(unsigned*)(b + IMSTRIDE)     = q1;   // px = 1
            *(unsigned*)(b + 2 * IMSTRIDE) = q2;   // px = 2
        }
    }
}

__global__ __launch_bounds__(256, 4)
void snn_kernel(const float* __restrict__ x,
                const float* __restrict__ w1,
                const float* __restrict__ b1,
                const float* __restrict__ w2,
                const float* __restrict__ b2,
                const float* __restrict__ wf,
                const float* __restrict__ bf,
                float* __restrict__ out, int B)
{
    __shared__ __align__(16) unsigned char s_im[2 * ZIMG];      // 17408 B
    __shared__ __align__(16) unsigned short s_z2h[2 * Z2PAR];   // 4896 B
    __shared__ __align__(16) float s_x[2 * 256];                // 2048 B
    __shared__ __align__(16) float s_w1[13 * 16];
    __shared__ float s_b1[13];

    const int tid  = threadIdx.x;
    const int wave = tid >> 6, lane = tid & 63;
    const int quad = lane >> 4, col = lane & 15;

    // ---- stage x / w1 / b1; zero both zimg buffers ----
    if (tid < 128)
        ((float4*)s_x)[tid] = ((const float4*)(x + (size_t)blockIdx.x * 512))[tid];
    if (tid < 208) s_w1[tid] = w1[tid];
    if (tid < 13)  s_b1[tid] = b1[tid];
    for (int i = tid; i < 2 * ZIMG / 16; i += 256)
        ((uint4*)s_im)[i] = make_uint4(0, 0, 0, 0);
    __syncthreads();

    // ---- LIF1 row ownership: 156 rows = 2 samples * 13 ic * 6 y ----
    const bool rowOwner = (tid < 156);
    int sA = 0, icA = 0, yA = 0;
    if (rowOwner) { sA = tid / 78; const int r = tid - 78 * sA; icA = r / 6; yA = r - 6 * icA; }

    float cur1a[6], v1a[6], i1a[6];
    if (rowOwner) conv1_row(s_x + sA * 256, s_w1 + icA * 16, s_b1[icA], yA, cur1a);
    #pragma unroll
    for (int j = 0; j < 6; ++j) { v1a[j] = 0.f; i1a[j] = 0.f; }

    const int pbOff = (9 * sA + 3 * yA) * IMSTRIDE + 16 * icA;

    // ---- A-fragments: per-row 3-level i8 split of w2 (sigma-permuted K) ----
    i32x4 A1[4], A2[4], A3[4];
    float Mrow;
    {
        const float* wrow = w2 + (size_t)(wave * 16 + col) * 208;
        float M = 1e-20f;
        for (int k = 0; k < 208; ++k) M = fmaxf(M, fabsf(wrow[k]));
        Mrow = M;
        const float inv = 127.0f / M;
        const float q1s = M * (1.0f / 127.0f);
        const float q2s = M * (1.0f / (127.0f * 127.0f));
        #pragma unroll
        for (int kt = 0; kt < 4; ++kt) {
            i32x4 w1v = {0, 0, 0, 0}, w2v = {0, 0, 0, 0}, w3v = {0, 0, 0, 0};
            #pragma unroll
            for (int j = 0; j < 16; ++j) {
                const int kp = kt * 64 + quad * 16 + j;
                const int W = kp >> 2, kx = kp & 3;
                const int ic = W >> 2, ky = ((W & 3) - ic) & 3;
                const float w = (ic < 13) ? wrow[ic * 16 + ky * 4 + kx] : 0.f;
                const float b1f = rintf(w * inv);
                const float r1  = fmaf(b1f, -q1s, w);
                const float b2f = rintf(r1 * inv * 127.0f);
                const float r2  = fmaf(b2f, -q2s, r1);
                const float b3f = rintf(r2 * inv * 127.0f * 127.0f);
                const int wi = j >> 2, sh = (j & 3) * 8;
                w1v[wi] |= ((int)b1f & 0xFF) << sh;
                w2v[wi] |= ((int)b2f & 0xFF) << sh;
                w3v[wi] |= ((int)b3f & 0xFF) << sh;
            }
            A1[kt] = w1v; A2[kt] = w2v; A3[kt] = w3v;
        }
    }
    float sc1[4], sc2[4], sc3[4];
    #pragma unroll
    for (int r = 0; r < 4; ++r) {
        const float Mr = __shfl(Mrow, quad * 4 + r);
        sc1[r] = Mr * (1.0f / 127.0f);
        sc2[r] = Mr * (1.0f / (127.0f * 127.0f));
        sc3[r] = Mr * (1.0f / (127.0f * 127.0f * 127.0f));
    }

    // ---- static per-lane: fc weights, b2, B-frag / z2 offsets ----
    float wf0[9], wf1[9];
    #pragma unroll
    for (int q = 0; q < 9; ++q) {
        wf0[q] = wf[lane * 9 + q];          // fc reads z2h[q*68 + lane] (oc = lane)
        wf1[q] = wf[576 + lane * 9 + q];
    }
    const float bfv0 = bf[0], bfv1 = bf[1];
    float b2r[4];
    #pragma unroll
    for (int r = 0; r < 4; ++r) b2r[r] = b2[wave * 16 + quad * 4 + r];

    int bpo[2];        // byte offset of B-frag within a zimg parity buffer
    int zwo[2];        // short offset of z2 write within a parity
    bool zv[2];
    #pragma unroll
    for (int nt = 0; nt < 2; ++nt) {
        const int n = nt * 16 + col;            // [0,32), valid < 18
        bpo[nt] = n * IMSTRIDE + quad * 16;
        zv[nt] = (n < 18);
        const int slz = n / 9, pos = n - slz * 9;
        zwo[nt] = slz * Z2S + pos * 68 + wave * 16 + quad * 4;
    }

    float v2[8], i2[8];
    #pragma unroll
    for (int p = 0; p < 8; ++p) { v2[p] = 0.f; i2[p] = 0.f; }
    float v3a = 0.f, i3a = 0.f, v3b = 0.f, i3b = 0.f, sum0 = 0.f, sum1 = 0.f;

    const int sG = blockIdx.x * 2 + wave;        // valid for waves 0,1
    float* outv = out + (size_t)2 * B;

    // fc + LIF3 for step tp (wave w < 2 handles sample w)
    auto fc_step = [&](const unsigned short* zs, int tp) {
        float p0 = 0.f, p1 = 0.f;
        #pragma unroll
        for (int q = 0; q < 9; ++q) {
            const float z = __uint_as_float(((unsigned)zs[q * 68 + lane]) << 16);
            p0 = fmaf(z, wf0[q], p0);
            p1 = fmaf(z, wf1[q], p1);
        }
        #pragma unroll
        for (int off = 32; off > 0; off >>= 1) {
            p0 += __shfl_xor(p0, off);
            p1 += __shfl_xor(p1, off);
        }
        const float c3a = p0 + bfv0, c3b = p1 + bfv1;
        const float vd0 = v3a + 0.1f * (i3a - v3a);
        const float vd1 = v3b + 0.1f * (i3b - v3b);
        i3a = i3a * 0.8f + c3a;
        i3b = i3b * 0.8f + c3b;
        const bool q0 = vd0 > 1.0f, q1 = vd1 > 1.0f;
        v3a = q0 ? 0.0f : vd0;
        v3b = q1 ? 0.0f : vd1;
        sum0 += q0 ? 1.0f : 0.0f;
        sum1 += q1 ? 1.0f : 0.0f;
        if (lane == 0)
            *(float2*)(outv + (size_t)tp * 2 * B + 2 * sG) = make_float2(v3a, v3b);
    };

    // One timestep, compile-time parity P at call sites.
    auto step = [&](int t, int P) {
        // ---- Phase A: LIF1 + scatter into zimg[P] ----
        if (rowOwner) lif1_row(v1a, i1a, cur1a, s_im + P * ZIMG + pbOff, icA, yA);
        __syncthreads();                 // the only barrier per step

        // ---- deferred fc for step t-1 (parity P^1); waves 2,3 skip ----
        if (t && wave < 2)
            fc_step(s_z2h + (P ^ 1) * Z2PAR + wave * Z2S, t - 1);

        // ---- GEMM: 6 acc chains (2 nt x 3 levels), 8 b128 loads ----
        const unsigned char* zbuf = s_im + P * ZIMG;
        i32x4 c1a = {0,0,0,0}, c1b = c1a;
        i32x4 c2a = c1a, c2b = c1a;
        i32x4 c3a_ = c1a, c3b_ = c1a;
        #pragma unroll
        for (int kt = 0; kt < 4; ++kt) {
            const i32x4 B0 = *(const i32x4*)(zbuf + bpo[0] + kt * 64);
            const i32x4 B1 = *(const i32x4*)(zbuf + bpo[1] + kt * 64);
            c1a  = __builtin_amdgcn_mfma_i32_16x16x64_i8(A1[kt], B0, c1a, 0, 0, 0);
            c1b  = __builtin_amdgcn_mfma_i32_16x16x64_i8(A1[kt], B1, c1b, 0, 0, 0);
            c2a  = __builtin_amdgcn_mfma_i32_16x16x64_i8(A2[kt], B0, c2a, 0, 0, 0);
            c2b  = __builtin_amdgcn_mfma_i32_16x16x64_i8(A2[kt], B1, c2b, 0, 0, 0);
            c3a_ = __builtin_amdgcn_mfma_i32_16x16x64_i8(A3[kt], B0, c3a_, 0, 0, 0);
            c3b_ = __builtin_amdgcn_mfma_i32_16x16x64_i8(A3[kt], B1, c3b_, 0, 0, 0);
        }

        // ---- LIF2 + z2 export into s_z2h[P] ----
        const i32x4 L1[2] = {c1a, c1b};
        const i32x4 L2[2] = {c2a, c2b};
        const i32x4 L3[2] = {c3a_, c3b_};
        unsigned short* z2b = s_z2h + P * Z2PAR;
        #pragma unroll
        for (int nt = 0; nt < 2; ++nt) {
            unsigned zbits[4];
            #pragma unroll
            for (int r = 0; r < 4; ++r) {
                const int p = nt * 4 + r;
                const float cur2 =
                    fmaf(sc1[r], (float)L1[nt][r],
                    fmaf(sc2[r], (float)L2[nt][r],
                    fmaf(sc3[r], (float)L3[nt][r], b2r[r])));
                const float vd = v2[p] + 0.1f * (i2[p] - v2[p]);
                i2[p] = i2[p] * 0.8f + cur2;
                const bool sp = vd > 1.0f;
                v2[p] = sp ? 0.0f : vd;
                zbits[r] = sp ? 0x3F80u : 0u;     // bf16 1.0
            }
            if (zv[nt]) {
                const unsigned lo = zbits[0] | (zbits[1] << 16);
                const unsigned hi = zbits[2] | (zbits[3] << 16);
                *(uint2*)(z2b + zwo[nt]) = make_uint2(lo, hi);
            }
        }
    };

    #pragma unroll 1
    for (int t = 0; t < NSTEPS; t += 2) {
        step(t, 0);
        step(t + 1, 1);
    }

    __syncthreads();
    if (wave < 2)
        fc_step(s_z2h + 1 * Z2PAR + wave * Z2S, NSTEPS - 1);

    if (wave < 2 && lane == 0)
        *(float2*)(out + (size_t)2 * sG) = make_float2(sum0, sum1);
}

extern "C" void kernel_launch(void* const* d_in, const int* in_sizes, int n_in,
                              void* d_out, int out_size, void* d_ws, size_t ws_size,
                              hipStream_t stream)
{
    const float* x  = (const float*)d_in[0];
    const float* w1 = (const float*)d_in[1];
    const float* b1 = (const float*)d_in[2];
    const float* w2 = (const float*)d_in[3];
    const float* b2 = (const float*)d_in[4];
    const float* wf = (const float*)d_in[5];
    const float* bf = (const float*)d_in[6];
    float* out = (float*)d_out;

    const int B = in_sizes[0] / 256;     // x is [B,1,16,16]
    const int grid = B / 2;              // 2 samples per block

    hipLaunchKernelGGL(snn_kernel, dim3(grid), dim3(256), 0, stream,
                       x, w1, b1, w2, b2, wf, bf, out, B);
}

// Round 10
// 356.023 us; speedup vs baseline: 2.6829x; 2.6829x over previous
//
#include <hip/hip_runtime.h>

// R10 = R8's proven shell (4 samples/block, 4 waves, i8 3-level MFMA,
// sigma-scatter, bf16 z2, deferred fc) + 2-step-ahead scatter pipelining.
//  - LIF1 runs 2 steps ahead of the GEMM; 4 z-image buffers (t mod 4).
//  - body(t): B-loads(t) issued first -> fc(t-1) -> MFMA(t) -> LIF2/z2(t)
//    -> LIF1+scatter(t+2) -> barrier. Scatter now has 2 barriers of slack
//    before its readers instead of 0.
//  - Hazards: scatter(t+2) vs GEMM-read(t+2): barriers t, t+1 between.
//    WAR vs GEMM(t-2): barriers t-2, t-1. z2 parity (t&1) as R8.
//  - __launch_bounds__(256,2) restored (R9's (256,4) forced VGPR=64 ->
//    2.1 GB scratch spills; register floor ~160 caps TLP at 2 waves/SIMD).

#define NSTEPS 100
#define IMSTRIDE 272
#define ZIMG (48 * IMSTRIDE)   // 13056 B per buffer; 4 buffers
#define Z2S 612                // shorts per (sample, step)
#define Z2T (4 * Z2S)          // shorts per t-parity (4 samples)

typedef __attribute__((ext_vector_type(4))) int i32x4;

// conv1 + 2x2 maxpool for one spike-row (sample, ic, y): 6 outputs
__device__ __forceinline__ void conv1_row(const float* __restrict__ xs,
                                          const float* __restrict__ w1s,
                                          float b1v, int y, float* cur) {
    float cr[2][12];
    #pragma unroll
    for (int rr = 0; rr < 2; ++rr) {
        const int cy = 2 * y + rr;
        #pragma unroll
        for (int cx = 0; cx < 12; ++cx) {
            float a = 0.f;
            #pragma unroll
            for (int ky = 0; ky < 4; ++ky)
            #pragma unroll
            for (int kx = 0; kx < 4; ++kx)
                a = fmaf(xs[(cy + ky) * 16 + cx + kx], w1s[ky * 4 + kx], a);
            cr[rr][cx] = a + b1v;
        }
    }
    #pragma unroll
    for (int px = 0; px < 6; ++px)
        cur[px] = fmaxf(fmaxf(cr[0][2 * px], cr[0][2 * px + 1]),
                        fmaxf(cr[1][2 * px], cr[1][2 * px + 1]));
}

// LIF1 step for one spike-row + sigma-permuted i8 scatter.
// pb = zimg_buffer_base + (9*sl + 3*y)*IMSTRIDE + 16*ic
__device__ __forceinline__ void lif1_row(float* v1, float* i1, const float* cur,
                                         unsigned char* pb, int ic, int y) {
    unsigned zb[6];
    #pragma unroll
    for (int xx = 0; xx < 6; ++xx) {
        const float vd = v1[xx] + 0.1f * (i1[xx] - v1[xx]);
        i1[xx] = i1[xx] * 0.8f + cur[xx];
        const bool sp = vd > 1.0f;
        v1[xx] = sp ? 0.0f : vd;
        zb[xx] = sp ? 1u : 0u;
    }
    const unsigned q0 = zb[0] | (zb[1] << 8) | (zb[2] << 16) | (zb[3] << 24);
    const unsigned q1 = zb[1] | (zb[2] << 8) | (zb[3] << 16) | (zb[4] << 24);
    const unsigned q2 = zb[2] | (zb[3] << 8) | (zb[4] << 16) | (zb[5] << 24);
    #pragma unroll
    for (int ky = 0; ky < 4; ++ky) {
        const int py = y - ky;
        if (0 <= py && py <= 2) {
            unsigned char* b = pb - ky * (3 * IMSTRIDE) + 4 * ((ky + ic) & 3);
            *(unsigned*)(b)                = q0;   // px = 0
            *(unsigned*)(b + IMSTRIDE)     = q1;   // px = 1
            *(unsigned*)(b + 2 * IMSTRIDE) = q2;   // px = 2
        }
    }
}

__global__ __launch_bounds__(256, 2)
void snn_kernel(const float* __restrict__ x,
                const float* __restrict__ w1,
                const float* __restrict__ b1,
                const float* __restrict__ w2,
                const float* __restrict__ b2,
                const float* __restrict__ wf,
                const float* __restrict__ bf,
                float* __restrict__ out, int B)
{
    __shared__ __align__(16) unsigned char s_im[4 * ZIMG];      // 52224 B
    __shared__ __align__(16) unsigned short s_z2h[2 * Z2T];     // 9792 B
    __shared__ __align__(16) float s_x[4 * 256];                // 4096 B
    __shared__ __align__(16) float s_w1[13 * 16];
    __shared__ float s_b1[13];

    const int tid  = threadIdx.x;
    const int wave = tid >> 6, lane = tid & 63;
    const int quad = lane >> 4, col = lane & 15;

    // ---- stage x / w1 / b1; zero all 4 zimg buffers ----
    ((float4*)(s_x + wave * 256))[lane] =
        ((const float4*)(x + (size_t)(blockIdx.x * 4 + wave) * 256))[lane];
    if (tid < 208) s_w1[tid] = w1[tid];
    if (tid < 13)  s_b1[tid] = b1[tid];
    for (int i = tid; i < 4 * ZIMG / 16; i += 256)
        ((uint4*)s_im)[i] = make_uint4(0, 0, 0, 0);
    __syncthreads();

    // ---- LIF1 row ownership: rows R = tid and tid+256 of 312 = 4*13*6 ----
    int sA, icA, yA, sB = 0, icB = 0, yB = 0;
    { const int R = tid;       sA = R / 78; int r = R - 78 * sA; icA = r / 6; yA = r - 6 * icA; }
    if (tid < 56) { const int R = tid + 256; sB = R / 78; int r = R - 78 * sB; icB = r / 6; yB = r - 6 * icB; }

    float cur1a[6], v1a[6], i1a[6], cur1b[6], v1b[6], i1b[6];
    conv1_row(s_x + sA * 256, s_w1 + icA * 16, s_b1[icA], yA, cur1a);
    if (tid < 56) conv1_row(s_x + sB * 256, s_w1 + icB * 16, s_b1[icB], yB, cur1b);
    #pragma unroll
    for (int j = 0; j < 6; ++j) { v1a[j] = i1a[j] = 0.f; v1b[j] = i1b[j] = 0.f; }

    const int pbOffA = (9 * sA + 3 * yA) * IMSTRIDE + 16 * icA;
    const int pbOffB = (9 * sB + 3 * yB) * IMSTRIDE + 16 * icB;

    // ---- A-fragments: per-row 3-level i8 split of w2 (sigma-permuted K) ----
    i32x4 A1[4], A2[4], A3[4];
    float Mrow;
    {
        const float* wrow = w2 + (size_t)(wave * 16 + col) * 208;
        float M = 1e-20f;
        for (int k = 0; k < 208; ++k) M = fmaxf(M, fabsf(wrow[k]));
        Mrow = M;
        const float inv = 127.0f / M;
        const float q1s = M * (1.0f / 127.0f);
        const float q2s = M * (1.0f / (127.0f * 127.0f));
        #pragma unroll
        for (int kt = 0; kt < 4; ++kt) {
            i32x4 w1v = {0, 0, 0, 0}, w2v = {0, 0, 0, 0}, w3v = {0, 0, 0, 0};
            #pragma unroll
            for (int j = 0; j < 16; ++j) {
                const int kp = kt * 64 + quad * 16 + j;
                const int W = kp >> 2, kx = kp & 3;
                const int ic = W >> 2, ky = ((W & 3) - ic) & 3;
                const float w = (ic < 13) ? wrow[ic * 16 + ky * 4 + kx] : 0.f;
                const float b1f = rintf(w * inv);
                const float r1  = fmaf(b1f, -q1s, w);
                const float b2f = rintf(r1 * inv * 127.0f);
                const float r2  = fmaf(b2f, -q2s, r1);
                const float b3f = rintf(r2 * inv * 127.0f * 127.0f);
                const int wi = j >> 2, sh = (j & 3) * 8;
                w1v[wi] |= ((int)b1f & 0xFF) << sh;
                w2v[wi] |= ((int)b2f & 0xFF) << sh;
                w3v[wi] |= ((int)b3f & 0xFF) << sh;
            }
            A1[kt] = w1v; A2[kt] = w2v; A3[kt] = w3v;
        }
    }
    float sc1[4], sc2[4], sc3[4];
    #pragma unroll
    for (int r = 0; r < 4; ++r) {
        const float Mr = __shfl(Mrow, quad * 4 + r);
        sc1[r] = Mr * (1.0f / 127.0f);
        sc2[r] = Mr * (1.0f / (127.0f * 127.0f));
        sc3[r] = Mr * (1.0f / (127.0f * 127.0f * 127.0f));
    }

    // ---- static per-lane: fc weights, b2, B-frag / z2 offsets ----
    float wf0[9], wf1[9];
    #pragma unroll
    for (int q = 0; q < 9; ++q) {
        wf0[q] = wf[lane * 9 + q];          // fc reads z2h[q*68 + lane] (oc = lane)
        wf1[q] = wf[576 + lane * 9 + q];
    }
    const float bfv0 = bf[0], bfv1 = bf[1];
    float b2r[4];
    #pragma unroll
    for (int r = 0; r < 4; ++r) b2r[r] = b2[wave * 16 + quad * 4 + r];

    int bpo[3];        // byte offset of B-frag within a zimg buffer
    int zwo[3];        // short offset of z2 write within a t-parity
    bool zv[3];
    #pragma unroll
    for (int nt = 0; nt < 3; ++nt) {
        const int n = nt * 16 + col;
        bpo[nt] = n * IMSTRIDE + quad * 16;
        zv[nt] = (n < 36);
        const int slz = n / 9, pos = n - slz * 9;
        zwo[nt] = slz * Z2S + pos * 68 + wave * 16 + quad * 4;
    }

    float v2[12], i2[12];
    #pragma unroll
    for (int p = 0; p < 12; ++p) { v2[p] = 0.f; i2[p] = 0.f; }
    float v3a = 0.f, i3a = 0.f, v3b = 0.f, i3b = 0.f, sum0 = 0.f, sum1 = 0.f;

    const int sG = blockIdx.x * 4 + wave;
    float* outv = out + (size_t)2 * B;

    // fc + LIF3 for step tp (wave w handles sample w)
    auto fc_step = [&](const unsigned short* zs, int tp) {
        float p0 = 0.f, p1 = 0.f;
        #pragma unroll
        for (int q = 0; q < 9; ++q) {
            const float z = __uint_as_float(((unsigned)zs[q * 68 + lane]) << 16);
            p0 = fmaf(z, wf0[q], p0);
            p1 = fmaf(z, wf1[q], p1);
        }
        #pragma unroll
        for (int off = 32; off > 0; off >>= 1) {
            p0 += __shfl_xor(p0, off);
            p1 += __shfl_xor(p1, off);
        }
        const float c3a = p0 + bfv0, c3b = p1 + bfv1;
        const float vd0 = v3a + 0.1f * (i3a - v3a);
        const float vd1 = v3b + 0.1f * (i3b - v3b);
        i3a = i3a * 0.8f + c3a;
        i3b = i3b * 0.8f + c3b;
        const bool q0 = vd0 > 1.0f, q1 = vd1 > 1.0f;
        v3a = q0 ? 0.0f : vd0;
        v3b = q1 ? 0.0f : vd1;
        sum0 += q0 ? 1.0f : 0.0f;
        sum1 += q1 ? 1.0f : 0.0f;
        if (lane == 0)
            *(float2*)(outv + (size_t)tp * 2 * B + 2 * sG) = make_float2(v3a, v3b);
    };

    // ---- prologue: scatter steps 0 and 1 into buffers 0,1 ----
    lif1_row(v1a, i1a, cur1a, s_im + pbOffA, icA, yA);
    if (tid < 56) lif1_row(v1b, i1b, cur1b, s_im + pbOffB, icB, yB);
    lif1_row(v1a, i1a, cur1a, s_im + ZIMG + pbOffA, icA, yA);
    if (tid < 56) lif1_row(v1b, i1b, cur1b, s_im + ZIMG + pbOffB, icB, yB);
    __syncthreads();

    // One timestep; p4 = t&3 is a compile-time literal at each call site.
    auto body = [&](int t, int p4) {
        // ---- issue GEMM B-loads for step t first ----
        const unsigned char* zbuf = s_im + p4 * ZIMG;
        i32x4 Bf0[4], Bf1[4], Bf2[4];
        #pragma unroll
        for (int kt = 0; kt < 4; ++kt) {
            Bf0[kt] = *(const i32x4*)(zbuf + bpo[0] + kt * 64);
            Bf1[kt] = *(const i32x4*)(zbuf + bpo[1] + kt * 64);
            Bf2[kt] = *(const i32x4*)(zbuf + bpo[2] + kt * 64);
        }

        // ---- deferred fc for step t-1 (its lgkm wait drains the loads) ----
        if (t) fc_step(s_z2h + ((p4 ^ 1) & 1) * Z2T + wave * Z2S, t - 1);

        // ---- MFMA: 9 chains (3 nt x 3 levels) ----
        i32x4 c1a = {0,0,0,0}, c1b = c1a, c1c = c1a;
        i32x4 c2a = c1a, c2b = c1a, c2c = c1a;
        i32x4 c3a_ = c1a, c3b_ = c1a, c3c = c1a;
        #pragma unroll
        for (int kt = 0; kt < 4; ++kt) {
            c1a  = __builtin_amdgcn_mfma_i32_16x16x64_i8(A1[kt], Bf0[kt], c1a, 0, 0, 0);
            c1b  = __builtin_amdgcn_mfma_i32_16x16x64_i8(A1[kt], Bf1[kt], c1b, 0, 0, 0);
            c1c  = __builtin_amdgcn_mfma_i32_16x16x64_i8(A1[kt], Bf2[kt], c1c, 0, 0, 0);
            c2a  = __builtin_amdgcn_mfma_i32_16x16x64_i8(A2[kt], Bf0[kt], c2a, 0, 0, 0);
            c2b  = __builtin_amdgcn_mfma_i32_16x16x64_i8(A2[kt], Bf1[kt], c2b, 0, 0, 0);
            c2c  = __builtin_amdgcn_mfma_i32_16x16x64_i8(A2[kt], Bf2[kt], c2c, 0, 0, 0);
            c3a_ = __builtin_amdgcn_mfma_i32_16x16x64_i8(A3[kt], Bf0[kt], c3a_, 0, 0, 0);
            c3b_ = __builtin_amdgcn_mfma_i32_16x16x64_i8(A3[kt], Bf1[kt], c3b_, 0, 0, 0);
            c3c  = __builtin_amdgcn_mfma_i32_16x16x64_i8(A3[kt], Bf2[kt], c3c, 0, 0, 0);
        }

        // ---- LIF2 + z2 export into parity t&1 ----
        const i32x4 L1[3] = {c1a, c1b, c1c};
        const i32x4 L2[3] = {c2a, c2b, c2c};
        const i32x4 L3[3] = {c3a_, c3b_, c3c};
        unsigned short* z2b = s_z2h + (p4 & 1) * Z2T;
        #pragma unroll
        for (int nt = 0; nt < 3; ++nt) {
            unsigned zbits[4];
            #pragma unroll
            for (int r = 0; r < 4; ++r) {
                const int p = nt * 4 + r;
                const float cur2 =
                    fmaf(sc1[r], (float)L1[nt][r],
                    fmaf(sc2[r], (float)L2[nt][r],
                    fmaf(sc3[r], (float)L3[nt][r], b2r[r])));
                const float vd = v2[p] + 0.1f * (i2[p] - v2[p]);
                i2[p] = i2[p] * 0.8f + cur2;
                const bool sp = vd > 1.0f;
                v2[p] = sp ? 0.0f : vd;
                zbits[r] = sp ? 0x3F80u : 0u;     // bf16 1.0
            }
            if (zv[nt]) {
                const unsigned lo = zbits[0] | (zbits[1] << 16);
                const unsigned hi = zbits[2] | (zbits[3] << 16);
                *(uint2*)(z2b + zwo[nt]) = make_uint2(lo, hi);
            }
        }

        // ---- LIF1 + scatter for step t+2 into buffer (p4+2)&3 ----
        if (t < NSTEPS - 2) {
            unsigned char* nb = s_im + ((p4 + 2) & 3) * ZIMG;
            lif1_row(v1a, i1a, cur1a, nb + pbOffA, icA, yA);
            if (tid < 56) lif1_row(v1b, i1b, cur1b, nb + pbOffB, icB, yB);
        }
        __syncthreads();
    };

    #pragma unroll 1
    for (int t = 0; t < NSTEPS; t += 4) {
        body(t, 0);
        body(t + 1, 1);
        body(t + 2, 2);
        body(t + 3, 3);
    }

    // final fc: z2 of step 99 (parity 1) written before body(99)'s barrier
    fc_step(s_z2h + 1 * Z2T + wave * Z2S, NSTEPS - 1);

    if (lane == 0)
        *(float2*)(out + (size_t)2 * sG) = make_float2(sum0, sum1);
}

extern "C" void kernel_launch(void* const* d_in, const int* in_sizes, int n_in,
                              void* d_out, int out_size, void* d_ws, size_t ws_size,
                              hipStream_t stream)
{
    const float* x  = (const float*)d_in[0];
    const float* w1 = (const float*)d_in[1];
    const float* b1 = (const float*)d_in[2];
    const float* w2 = (const float*)d_in[3];
    const float* b2 = (const float*)d_in[4];
    const float* wf = (const float*)d_in[5];
    const float* bf = (const float*)d_in[6];
    float* out = (float*)d_out;

    const int B = in_sizes[0] / 256;     // x is [B,1,16,16]
    const int grid = B / 4;              // 4 samples per block

    hipLaunchKernelGGL(snn_kernel, dim3(grid), dim3(256), 0, stream,
                       x, w1, b1, w2, b2, wf, bf, out, B);
}